// Round 7
// baseline (308.962 us; speedup 1.0000x reference)
//
#include <hip/hip_runtime.h>

// MHA: B=2, S=2048, D=1024, H=16, DK=64. I/O bf16 (harness-confirmed R4);
// dual fp32 path retained via runtime detect. mask int32.
//
// Pipeline (ws 16 MB; d_out doubles as V scratch):
//   0) detect: classify d_in[0] bf16 vs fp32 -> flag in ws
//   1) gemmk<128,64,128,0>: Q/K/V proj (one launch, z selects tensor).
//        z=0: Qh [B,H,S,DK] pre-scaled by 0.125*log2e; z=1: Kh;
//        z=2: Vt [B,H,DK,S] transposed.
//   2) attn (R11, verbatim): flash, 128 q-rows/block (32/wave, 2 q-tiles),
//        64 keys/iter, swapped score MFMA, packed P b64/b128 round-trip.
//   3) gemmk<128,64,128,1>: out = ctx @ Wo^T -> d_out.
//
// MFMA 16x16x32 bf16 layouts (verified):
//   A: lane holds A[m=lane&15][k=(lane>>4)*8+j]
//   B: lane holds B[k=(lane>>4)*8+j][n=lane&15]
//   C/D: col=lane&15, row=(lane>>4)*4+reg
//
// R4: no u16/bf16 punning (TBAA reorder -> NaN).
// R5/R6: direct K/V + VGPR-roundtrip staging = latency bound.
// R8 REGRESSION: dual MFMA orientation in gemm K-loop.
// R9: BK=64 > BK=128 ... at the OLD bottleneck (superseded by R16 model).
// R10 FAILED: ds_read_b64_tr_b16 gather model wrong.
// R11: swapped-MFMA packed-P attn 85.6 -> 75.6 us.
// R12/R13/R15: gemm schedule experiments (dbuf, 2x occupancy, depth-3
//   counted vmcnt) ALL flat-to-worse at 77-90 us.
// R16 MODEL: time tracks K-STEP COUNT, not FLOPs or schedule: both gemms
//   = 16 steps = ~80 us (out-proj has half the FLOPs of QKV, same time;
//   ~5000 cyc/step vs ~400 cyc pipe work). Per-step fixed memory-round-
//   trip tax none of the schedules shortened. Lever: FEWER steps.
//   -> BK=128 (8 steps), TM=128/TN=64 both gemms, 32 MFMA / 24 ds_read
//   per wave-step, LDS 48KB single buffer, proven 2-barrier loop.
//   attn reverted to R11-exact. Falsifier: gemms still ~80 us => model
//   dead, next probe isolates non-loop cost.

typedef __bf16 bf16x8 __attribute__((ext_vector_type(8)));
typedef __bf16 bf16x4 __attribute__((ext_vector_type(4)));
typedef float f32x4 __attribute__((ext_vector_type(4)));

#define B_ 2
#define S_ 2048
#define D_ 1024
#define H_ 16
#define DK_ 64
#define QSCALE 0.18033688011112042f  // 0.125 * log2(e)

// ---------------------------------------------------------------------------
__global__ void detect_dtype(const unsigned int* __restrict__ qw,
                             int* __restrict__ flag) {
  int cnt = 0;
#pragma unroll
  for (int i = 0; i < 4; ++i) {
    unsigned int w = qw[threadIdx.x + 64 * i];
    int e = (w >> 7) & 0xFF;
    cnt += (e >= 100 && e <= 140) ? 1 : 0;
  }
#pragma unroll
  for (int off = 32; off > 0; off >>= 1) cnt += __shfl_down(cnt, off, 64);
  if (threadIdx.x == 0) *flag = (cnt >= 128) ? 0 : 1;
}

__device__ __forceinline__ bf16x8 load8cvt(const void* base, size_t eoff,
                                           bool f32) {
  if (!f32) return *(const bf16x8*)((const __bf16*)base + eoff);
  const float* p = (const float*)base + eoff;
  bf16x8 r;
#pragma unroll
  for (int j = 0; j < 8; ++j) r[j] = (__bf16)p[j];
  return r;
}

// async 16B global -> LDS (lds dest = wave-uniform base + lane*16)
__device__ __forceinline__ void async_cp16(const __bf16* g, __bf16* l) {
  __builtin_amdgcn_global_load_lds(
      (const __attribute__((address_space(1))) unsigned int*)g,
      (__attribute__((address_space(3))) unsigned int*)l, 16, 0, 0);
}

// ---------------------------------------------------------------------------
// GEMM (R16): C[M,N] = X[M,K] @ W[N,K]^T. TM x TN tile, BK=128 (8 K-steps),
// single LDS buffer, proven 2-barrier K-step: {barrier; stage; barrier;
// compute}. Per wave-step: 32 MFMA, 24 ds_read_b128 (4 h-chunks of k=32).
// LDS [rows][BK]; 16B chunks (16/row) XOR-swizzled: phys j = jl ^ (row&7)
// (low-3-bit XOR, bijective; read lanes 2-way bank alias = free).
// Staging: linear LDS dest + pre-swizzled global source (rule #21).
// MODE=1 A layout [B,H,S,DK]: k=(h_plane,dk); chunk jl covers plane
// (jl>>3) offset (jl&7)*8; koff advances (k0>>6) planes.
// f32 fallback: same loop shape, reg-staged converts.
// ---------------------------------------------------------------------------
template <int TM, int TN, int BK, int MODE>
__global__ __launch_bounds__(256) void gemmk(
    const void* X0, const void* X1, const void* X2,
    const void* W0, const void* W1, const void* W2,
    void* O0, void* O1, void* O2, const int* __restrict__ dflag) {
  constexpr int Kd = 1024, Nd = 1024;
  constexpr int MI = TM / 32;           // m-frags per wave
  constexpr int NI = TN / 32;           // n-frags per wave
  constexpr int HC = BK / 32;           // k-chunks per K-step
  constexpr int CPR = BK / 8;           // 8-elem groups per row
  constexpr int ACH = TM * BK / 2048;   // cp16 per wave for A
  constexpr int BCH = TN * BK / 2048;   // cp16 per wave for B
  constexpr int AFI = TM * BK / 2048;   // f32-fallback iters for A
  constexpr int BFI = TN * BK / 2048;   // f32-fallback iters for B
  const void* X = (blockIdx.z == 0) ? X0 : (blockIdx.z == 1 ? X1 : X2);
  const void* W = (blockIdx.z == 0) ? W0 : (blockIdx.z == 1 ? W1 : W2);
  void* O = (blockIdx.z == 0) ? O0 : (blockIdx.z == 1 ? O1 : O2);
  const bool f32io = (*dflag != 0);

  __shared__ __attribute__((aligned(16))) __bf16 As[TM * BK];
  __shared__ __attribute__((aligned(16))) __bf16 Bs[TN * BK];

  const int m0 = blockIdx.x * TM;
  const int n0 = blockIdx.y * TN;
  const int t = threadIdx.x;
  const int lane = t & 63, wave = t >> 6;
  const int l15 = lane & 15, quad = lane >> 4;
  const int wm = (wave >> 1) * (TM / 2);
  const int wn = (wave & 1) * (TN / 2);

  const __bf16* gA[ACH];
  int ldsAoff[ACH];
#pragma unroll
  for (int i = 0; i < ACH; ++i) {
    int c = (wave * ACH + i) * 64 + lane;       // global 16B-chunk id
    int row = c / CPR, j = c % CPR;
    int jl = j ^ (row & 7);
    ldsAoff[i] = (wave * ACH + i) * 512;        // linear dest, 512 elem/instr
    if (MODE == 0) {
      gA[i] = (const __bf16*)X + (size_t)(m0 + row) * Kd + jl * 8;
    } else {
      int gm = m0 + row;
      gA[i] = (const __bf16*)X + (size_t)(gm >> 11) * (H_ * S_ * DK_) +
              (size_t)(jl >> 3) * (S_ * DK_) +
              (size_t)(gm & (S_ - 1)) * DK_ + (jl & 7) * 8;
    }
  }
  const __bf16* gB[BCH];
  int ldsBoff[BCH];
#pragma unroll
  for (int i = 0; i < BCH; ++i) {
    int c = (wave * BCH + i) * 64 + lane;
    int row = c / CPR, j = c % CPR;
    int jl = j ^ (row & 7);
    ldsBoff[i] = (wave * BCH + i) * 512;
    gB[i] = (const __bf16*)W + (size_t)(n0 + row) * Kd + jl * 8;
  }

  f32x4 acc[MI][NI] = {};

  for (int k0 = 0; k0 < Kd; k0 += BK) {
    __syncthreads();
    if (!f32io) {
      if (MODE == 0) {
#pragma unroll
        for (int i = 0; i < ACH; ++i) async_cp16(gA[i] + k0, &As[ldsAoff[i]]);
      } else {
        const size_t koff = (size_t)(k0 >> 6) * (S_ * DK_);
#pragma unroll
        for (int i = 0; i < ACH; ++i) async_cp16(gA[i] + koff, &As[ldsAoff[i]]);
      }
#pragma unroll
      for (int i = 0; i < BCH; ++i) async_cp16(gB[i] + k0, &Bs[ldsBoff[i]]);
    } else {
#pragma unroll
      for (int i = 0; i < AFI; ++i) {
        int c = t + 256 * i;
        int row = c / CPR, j = c % CPR;
        int jl = j ^ (row & 7);
        bf16x8 xv;
        if (MODE == 0) {
          xv = load8cvt(X, (size_t)(m0 + row) * Kd + k0 + jl * 8, true);
        } else {
          int gm = m0 + row, gk = k0 + jl * 8;
          xv = *(const bf16x8*)((const __bf16*)X +
                ((((size_t)(gm >> 11) * H_ + (gk >> 6)) * S_) +
                 (gm & (S_ - 1))) * DK_ + (gk & (DK_ - 1)));
        }
        *(bf16x8*)&As[row * BK + j * 8] = xv;
      }
#pragma unroll
      for (int i = 0; i < BFI; ++i) {
        int c = t + 256 * i;
        int row = c / CPR, j = c % CPR;
        int jl = j ^ (row & 7);
        bf16x8 wv = load8cvt(W, (size_t)(n0 + row) * Kd + k0 + jl * 8, true);
        *(bf16x8*)&Bs[row * BK + j * 8] = wv;
      }
    }
    __syncthreads();

#pragma unroll
    for (int h = 0; h < HC; ++h) {
      bf16x8 af[MI], bfr[NI];
#pragma unroll
      for (int mi = 0; mi < MI; ++mi) {
        int row = wm + mi * 16 + l15;
        af[mi] = *(const bf16x8*)&As[row * BK +
                                     (((h * 4 + quad) ^ (row & 7)) << 3)];
      }
#pragma unroll
      for (int ni = 0; ni < NI; ++ni) {
        int row = wn + ni * 16 + l15;
        bfr[ni] = *(const bf16x8*)&Bs[row * BK +
                                      (((h * 4 + quad) ^ (row & 7)) << 3)];
      }
#pragma unroll
      for (int mi = 0; mi < MI; ++mi)
#pragma unroll
        for (int ni = 0; ni < NI; ++ni)
          acc[mi][ni] = __builtin_amdgcn_mfma_f32_16x16x32_bf16(
              af[mi], bfr[ni], acc[mi][ni], 0, 0, 0);
    }
  }

  const float oscale = (MODE == 0 && blockIdx.z == 0) ? QSCALE : 1.0f;
#pragma unroll
  for (int mi = 0; mi < MI; ++mi) {
#pragma unroll
    for (int ni = 0; ni < NI; ++ni) {
      int mbase = m0 + wm + mi * 16 + quad * 4;
      int n = n0 + wn + ni * 16 + l15;
      if (MODE == 0 && blockIdx.z == 2) {
        int b = mbase >> 11, sb = mbase & (S_ - 1);
        int h = n >> 6, dk = n & (DK_ - 1);
        bf16x4 pk;
#pragma unroll
        for (int r = 0; r < 4; ++r) pk[r] = (__bf16)acc[mi][ni][r];
        *(bf16x4*)&((__bf16*)O)[((size_t)(b * H_ + h) * DK_ + dk) * S_ + sb] = pk;
      } else {
#pragma unroll
        for (int r = 0; r < 4; ++r) {
          int m = mbase + r;
          float val = acc[mi][ni][r] * oscale;
          if (MODE == 0) {
            int b = m >> 11, s = m & (S_ - 1);
            int h = n >> 6, dk = n & (DK_ - 1);
            ((__bf16*)O)[((size_t)(b * H_ + h) * S_ + s) * DK_ + dk] = (__bf16)val;
          } else {
            size_t idx = (size_t)m * Nd + n;
            if (f32io) ((float*)O)[idx] = val;
            else       ((__bf16*)O)[idx] = (__bf16)val;
          }
        }
      }
    }
  }
}

// ---------------------------------------------------------------------------
// Flash attention, R11 form (verbatim, proven 75.6 us): 128 q-rows/block
// (32/wave as 2 q-tiles), 64 keys/iter, grid 512. Swapped score MFMA:
// s = mfma(Kfrag, Qfrag, bias) -> lane holds s[key=quad*4+r][q=l15].
// P per wave per q-tile: [16 q][64 key] rows of 128B, 16B chunks XOR-
// swizzled by (l15&7). Store: one ds_write_b64 per (qt,tt); read: one
// ds_read_b128 per (qt,kt) -> PV A-frag directly. K/V frags read once,
// shared by both q-tiles. Mask as per-key f32x4 bias init. Wave-private
// P: in-order LDS, no barriers; asm fence pins store phase above reads.
// ---------------------------------------------------------------------------
__global__ __launch_bounds__(256, 2) void attn(
    const __bf16* Qh, const __bf16* __restrict__ Kh,
    const __bf16* __restrict__ Vt, const int* __restrict__ mask,
    __bf16* Out) {
  __shared__ __attribute__((aligned(16))) __bf16 Ks[2][4096];
  __shared__ __attribute__((aligned(16))) __bf16 Vs[2][4096];
  __shared__ __attribute__((aligned(16))) __bf16 P[4][2048];  // wave: 2 x [16][64]

  const int t = threadIdx.x;
  const int lane = t & 63, wave = t >> 6;
  const int l15 = lane & 15, quad = lane >> 4;
  const int qb = blockIdx.x & 15;   // 16 q-blocks of 128
  const int bh = blockIdx.x >> 4;   // b*H + h
  const int b = bh >> 4;
  const int q0 = qb * 128 + wave * 32;

  const __bf16* Q = Qh + (size_t)bh * S_ * DK_;
  const __bf16* K = Kh + (size_t)bh * S_ * DK_;
  const __bf16* V = Vt + (size_t)bh * DK_ * S_;   // [dk][s]
  const int* mk = mask + b * S_;

  bf16x8 qf[2][2];
#pragma unroll
  for (int qt = 0; qt < 2; ++qt) {
    qf[qt][0] = *(const bf16x8*)&Q[(size_t)(q0 + qt * 16 + l15) * DK_ + quad * 8];
    qf[qt][1] = *(const bf16x8*)&Q[(size_t)(q0 + qt * 16 + l15) * DK_ + 32 + quad * 8];
  }

  f32x4 o[2][4] = {};
  float lsum[2] = {0.f, 0.f};

  // loop-invariant P element offsets (within P[wave], before qt*1024)
  int pst[4], prd[2];
#pragma unroll
  for (int tt = 0; tt < 4; ++tt)
    pst[tt] = l15 * 64 + (((tt * 2 + (quad >> 1)) ^ (l15 & 7)) << 3) +
              (quad & 1) * 4;
#pragma unroll
  for (int kt = 0; kt < 2; ++kt)
    prd[kt] = l15 * 64 + (((kt * 4 + quad) ^ (l15 & 7)) << 3);

  // prologue: stage tile 0 into buf 0
#pragma unroll
  for (int i = 0; i < 2; ++i) {
    int l = wave * 128 + i * 64 + lane;
    int row = l >> 3, jg = (l & 7) ^ (row & 7);
    async_cp16(K + (size_t)row * DK_ + jg * 8, &Ks[0][(size_t)(l - lane) * 8]);
    async_cp16(V + (size_t)row * S_ + jg * 8, &Vs[0][(size_t)(l - lane) * 8]);
  }
  __syncthreads();

  for (int kb = 0; kb < S_; kb += 64) {
    const int cur = (kb >> 6) & 1;
    if (kb + 64 < S_) {
#pragma unroll
      for (int i = 0; i < 2; ++i) {
        int l = wave * 128 + i * 64 + lane;
        int row = l >> 3, jg = (l & 7) ^ (row & 7);
        async_cp16(K + (size_t)(kb + 64 + row) * DK_ + jg * 8,
                   &Ks[cur ^ 1][(size_t)(l - lane) * 8]);
        async_cp16(V + (size_t)row * S_ + (kb + 64) + jg * 8,
                   &Vs[cur ^ 1][(size_t)(l - lane) * 8]);
      }
    }

    // ---- scores (SWAPPED): s[key=quad*4+r][q=l15]; K frags shared ----
    const __bf16* ks = &Ks[cur][0];
    f32x4 s[2][4];
#pragma unroll
    for (int tt = 0; tt < 4; ++tt) {
      int row = tt * 16 + l15;
      bf16x8 kf0 = *(const bf16x8*)&ks[row * 64 + ((quad ^ (l15 & 7)) << 3)];
      bf16x8 kf1 = *(const bf16x8*)&ks[row * 64 + (((4 + quad) ^ (l15 & 7)) << 3)];
      // per-key mask bias: keys tt*16 + quad*4 .. +3
      int4 m4 = *(const int4*)&mk[kb + tt * 16 + quad * 4];
      f32x4 z;
      z[0] = m4.x ? 0.f : -1e9f;
      z[1] = m4.y ? 0.f : -1e9f;
      z[2] = m4.z ? 0.f : -1e9f;
      z[3] = m4.w ? 0.f : -1e9f;
      f32x4 z0 = __builtin_amdgcn_mfma_f32_16x16x32_bf16(kf0, qf[0][0], z, 0, 0, 0);
      s[0][tt] = __builtin_amdgcn_mfma_f32_16x16x32_bf16(kf1, qf[0][1], z0, 0, 0, 0);
      f32x4 z1 = __builtin_amdgcn_mfma_f32_16x16x32_bf16(kf0, qf[1][0], z, 0, 0, 0);
      s[1][tt] = __builtin_amdgcn_mfma_f32_16x16x32_bf16(kf1, qf[1][1], z1, 0, 0, 0);
    }

    // ---- V fragments (issue while exp phase runs; shared by q-tiles) ----
    const __bf16* vs = &Vs[cur][0];
    bf16x8 vf[2][4];
#pragma unroll
    for (int kt = 0; kt < 2; ++kt)
#pragma unroll
      for (int nt = 0; nt < 4; ++nt) {
        int dk = nt * 16 + l15;
        vf[kt][nt] =
            *(const bf16x8*)&vs[dk * 64 + (((kt * 4 + quad) ^ (l15 & 7)) << 3)];
      }

    // ---- exp2 + packed P store: one b64 per (qt,tt) ----
#pragma unroll
    for (int qt = 0; qt < 2; ++qt) {
      float acc = 0.f;
#pragma unroll
      for (int tt = 0; tt < 4; ++tt) {
        bf16x4 pk;
#pragma unroll
        for (int r = 0; r < 4; ++r) {
          float e = __builtin_exp2f(s[qt][tt][r]);   // Q carries 0.125*log2e
          acc += e;
          pk[r] = (__bf16)e;
        }
        *(bf16x4*)&P[wave][qt * 1024 + pst[tt]] = pk;
      }
      lsum[qt] += acc;
    }

    asm volatile("" ::: "memory");  // pin P stores above the P reads (TBAA)

    // ---- PV: P read back as A-frag via b128; V frags shared ----
#pragma unroll
    for (int qt = 0; qt < 2; ++qt)
#pragma unroll
      for (int kt = 0; kt < 2; ++kt) {
        bf16x8 pf = *(const bf16x8*)&P[wave][qt * 1024 + prd[kt]];
#pragma unroll
        for (int nt = 0; nt < 4; ++nt)
          o[qt][nt] = __builtin_amdgcn_mfma_f32_16x16x32_bf16(
              pf, vf[kt][nt], o[qt][nt], 0, 0, 0);
      }

    __syncthreads();  // drains staging vmcnt; separates buffer reuse
  }

  // lsum finish: all keys of a q-row live in lanes with same l15
#pragma unroll
  for (int qt = 0; qt < 2; ++qt) {
    float v = lsum[qt];
    v += __shfl_xor(v, 16, 64);
    v += __shfl_xor(v, 32, 64);
    lsum[qt] = v;  // every lane: sum for q = l15 (of tile qt)
  }

#pragma unroll
  for (int qt = 0; qt < 2; ++qt) {
    float rinv[4];
#pragma unroll
    for (int r = 0; r < 4; ++r)
      rinv[r] = 1.0f / __shfl(lsum[qt], quad * 4 + r, 64);
#pragma unroll
    for (int nt = 0; nt < 4; ++nt)
#pragma unroll
      for (int r = 0; r < 4; ++r) {
        int qrow = q0 + qt * 16 + quad * 4 + r;
        Out[(size_t)bh * S_ * DK_ + (size_t)qrow * DK_ + nt * 16 + l15] =
            (__bf16)(o[qt][nt][r] * rinv[r]);
      }
  }
}

extern "C" void kernel_launch(void* const* d_in, const int* in_sizes, int n_in,
                              void* d_out, int out_size, void* d_ws, size_t ws_size,
                              hipStream_t stream) {
  const void* q = d_in[0];
  const void* k = d_in[1];
  const void* v = d_in[2];
  const int* mask = (const int*)d_in[3];
  const void* Wq = d_in[4];
  const void* Wk = d_in[5];
  const void* Wv = d_in[6];
  const void* Wo = d_in[7];

  const size_t NE = (size_t)B_ * H_ * S_ * DK_;  // 4,194,304 elems
  __bf16* Qh = (__bf16*)d_ws;                    // ws[0 : 8M)  -> becomes ctx
  __bf16* Kh = Qh + NE;                          // ws[8M : 16M)
  int* dflag = (int*)((char*)d_ws + 2 * NE * sizeof(__bf16));
  __bf16* Vt = (__bf16*)d_out;                   // scratch; dead before final write

  detect_dtype<<<1, 64, 0, stream>>>((const unsigned int*)q, dflag);
  dim3 g1(32, 16, 3);
  gemmk<128, 64, 128, 0><<<g1, 256, 0, stream>>>(q, k, v, Wq, Wk, Wv, Qh, Kh,
                                                 Vt, dflag);
  attn<<<512, 256, 0, stream>>>(Qh, Kh, Vt, mask, Qh);
  dim3 g2(32, 16, 1);
  gemmk<128, 64, 128, 1><<<g2, 256, 0, stream>>>(Qh, Qh, Qh, Wo, Wo, Wo,
                                                 d_out, d_out, d_out, dflag);
}

// Round 8
// 256.251 us; speedup vs baseline: 1.2057x; 1.2057x over previous
//
#include <hip/hip_runtime.h>

// MHA: B=2, S=2048, D=1024, H=16, DK=64. I/O bf16 (harness-confirmed R4);
// dual fp32 path retained via runtime detect. mask int32.
//
// Pipeline (ws 16 MB; d_out doubles as V scratch):
//   0) detect: classify d_in[0] bf16 vs fp32 -> flag in ws
//   1) gemmk<128,128,0>: Q/K/V proj (one launch, z selects tensor).
//        z=0: Qh [B,H,S,DK] pre-scaled by 0.125*log2e; z=1: Kh;
//        z=2: Vt [B,H,DK,S] transposed.
//   2) attn (R11, verbatim): flash, 128 q-rows/block (32/wave, 2 q-tiles),
//        64 keys/iter, swapped score MFMA, packed P b64/b128 round-trip.
//   3) gemmk<64,128,1>: out = ctx @ Wo^T -> d_out (512 blocks).
//
// MFMA 16x16x32 bf16 layouts (verified):
//   A: lane holds A[m=lane&15][k=(lane>>4)*8+j]
//   B: lane holds B[k=(lane>>4)*8+j][n=lane&15]
//   C/D: col=lane&15, row=(lane>>4)*4+reg
//
// R4: no u16/bf16 punning (TBAA reorder -> NaN).
// R5/R6: direct K/V + VGPR-roundtrip staging = latency bound.
// R8 REGRESSION: dual MFMA orientation in gemm K-loop.
// R9: BK=64 gemms win (re-confirmed by R16).
// R10 FAILED: ds_read_b64_tr_b16 gather model wrong.
// R11: swapped-MFMA packed-P attn 85.6 -> 75.6 us.
// R12/R13/R15: gemm schedule experiments (dbuf, 2x occupancy, depth-3
//   counted vmcnt) ALL flat-to-worse at 77-90 us.
// R16 REGRESSION (77->113, 4.7M bank conflicts): BK=128's 16-chunk XOR
//   swizzle aliases banks (low-3-bit XOR can't separate chunks 8-15).
// R17 MODEL (fits all 6 data points): block-step time ~constant 2.2us
//   across schedules; throughput = blocks/CU x FLOP/step.
//   m97@4096^3: 4 x 2MFLOP / 2.3us = 890TF (ok). Ours: 2.75 x 1MFLOP /
//   2.2us = 320TF (ok). R15 counted-vmcnt shortened step (1.85us) but
//   cost blocks/CU (ok). Lever: FLOP/step -> m97-EXACT 128x128 tile,
//   BK=64, proven zero-conflict swizzle, proven 2-barrier loop.
//   Falsifier: QKV >= 70us kills the model -> disasm next, not guesses.

typedef __bf16 bf16x8 __attribute__((ext_vector_type(8)));
typedef __bf16 bf16x4 __attribute__((ext_vector_type(4)));
typedef float f32x4 __attribute__((ext_vector_type(4)));

#define B_ 2
#define S_ 2048
#define D_ 1024
#define H_ 16
#define DK_ 64
#define QSCALE 0.18033688011112042f  // 0.125 * log2(e)

// ---------------------------------------------------------------------------
__global__ void detect_dtype(const unsigned int* __restrict__ qw,
                             int* __restrict__ flag) {
  int cnt = 0;
#pragma unroll
  for (int i = 0; i < 4; ++i) {
    unsigned int w = qw[threadIdx.x + 64 * i];
    int e = (w >> 7) & 0xFF;
    cnt += (e >= 100 && e <= 140) ? 1 : 0;
  }
#pragma unroll
  for (int off = 32; off > 0; off >>= 1) cnt += __shfl_down(cnt, off, 64);
  if (threadIdx.x == 0) *flag = (cnt >= 128) ? 0 : 1;
}

__device__ __forceinline__ bf16x8 load8cvt(const void* base, size_t eoff,
                                           bool f32) {
  if (!f32) return *(const bf16x8*)((const __bf16*)base + eoff);
  const float* p = (const float*)base + eoff;
  bf16x8 r;
#pragma unroll
  for (int j = 0; j < 8; ++j) r[j] = (__bf16)p[j];
  return r;
}

// async 16B global -> LDS (lds dest = wave-uniform base + lane*16)
__device__ __forceinline__ void async_cp16(const __bf16* g, __bf16* l) {
  __builtin_amdgcn_global_load_lds(
      (const __attribute__((address_space(1))) unsigned int*)g,
      (__attribute__((address_space(3))) unsigned int*)l, 16, 0, 0);
}

// ---------------------------------------------------------------------------
// GEMM (R17): C[M,N] = X[M,K] @ W[N,K]^T, TM x TN tile, BK=64, single LDS
// buffer, proven 2-barrier K-step {barrier; stage; barrier; compute}.
// Wave grid 2x2: wave covers (TM/2) x (TN/2); MI=TM/32, NI=TN/32 frags.
// Per wave-step (128x128): 32 MFMA, 16 ds_read_b128 = m97's exact ratio.
// LDS [rows][64]; 16B chunks (8/row) XOR-swizzled (phys j = jl ^ (row&7))
// -- the PROVEN zero-conflict BK=64 layout (R11-R15: conflicts = 0).
// Staging: linear LDS dest + pre-swizzled global source (rule #21).
// f32 fallback: same loop shape, reg-staged converts.
// ---------------------------------------------------------------------------
template <int TM, int TN, int MODE>
__global__ __launch_bounds__(256) void gemmk(
    const void* X0, const void* X1, const void* X2,
    const void* W0, const void* W1, const void* W2,
    void* O0, void* O1, void* O2, const int* __restrict__ dflag) {
  constexpr int Kd = 1024, Nd = 1024;
  constexpr int MI = TM / 32;     // m-frags per wave
  constexpr int NI = TN / 32;     // n-frags per wave
  constexpr int ACH = TM / 32;    // A staging cp16 per wave (1KB each)
  constexpr int BCH = TN / 32;    // B staging cp16 per wave
  const void* X = (blockIdx.z == 0) ? X0 : (blockIdx.z == 1 ? X1 : X2);
  const void* W = (blockIdx.z == 0) ? W0 : (blockIdx.z == 1 ? W1 : W2);
  void* O = (blockIdx.z == 0) ? O0 : (blockIdx.z == 1 ? O1 : O2);
  const bool f32io = (*dflag != 0);

  __shared__ __attribute__((aligned(16))) __bf16 As[TM * 64];
  __shared__ __attribute__((aligned(16))) __bf16 Bs[TN * 64];

  const int m0 = blockIdx.x * TM;
  const int n0 = blockIdx.y * TN;
  const int t = threadIdx.x;
  const int lane = t & 63, wave = t >> 6;
  const int l15 = lane & 15, quad = lane >> 4;
  const int wm = (wave >> 1) * (TM / 2);
  const int wn = (wave & 1) * (TN / 2);

  const __bf16* gA[ACH];
  int ldsAoff[ACH];
#pragma unroll
  for (int i = 0; i < ACH; ++i) {
    int c = (wave * ACH + i) * 64 + lane;
    int row = c >> 3, j = c & 7;
    int jl = j ^ (row & 7);
    ldsAoff[i] = (wave * ACH + i) * 512;
    if (MODE == 0) {
      gA[i] = (const __bf16*)X + (size_t)(m0 + row) * Kd + jl * 8;
    } else {
      int gm = m0 + row;
      gA[i] = (const __bf16*)X + (size_t)(gm >> 11) * (H_ * S_ * DK_) +
              (size_t)(gm & (S_ - 1)) * DK_ + jl * 8;
    }
  }
  const __bf16* gB[BCH];
  int ldsBoff[BCH];
#pragma unroll
  for (int i = 0; i < BCH; ++i) {
    int c = (wave * BCH + i) * 64 + lane;
    int row = c >> 3, j = c & 7;
    int jl = j ^ (row & 7);
    ldsBoff[i] = (wave * BCH + i) * 512;
    gB[i] = (const __bf16*)W + (size_t)(n0 + row) * Kd + jl * 8;
  }

  f32x4 acc[MI][NI] = {};

  for (int k0 = 0; k0 < Kd; k0 += 64) {
    __syncthreads();
    if (!f32io) {
      if (MODE == 0) {
#pragma unroll
        for (int i = 0; i < ACH; ++i) async_cp16(gA[i] + k0, &As[ldsAoff[i]]);
      } else {
        const size_t koff = (size_t)(k0 >> 6) * (S_ * DK_);
#pragma unroll
        for (int i = 0; i < ACH; ++i) async_cp16(gA[i] + koff, &As[ldsAoff[i]]);
      }
#pragma unroll
      for (int i = 0; i < BCH; ++i) async_cp16(gB[i] + k0, &Bs[ldsBoff[i]]);
    } else {
#pragma unroll
      for (int i = 0; i < TM / 32; ++i) {
        int c = t + 256 * i;
        int row = c >> 3, j = c & 7;
        int jl = j ^ (row & 7);
        bf16x8 xv;
        if (MODE == 0) {
          xv = load8cvt(X, (size_t)(m0 + row) * Kd + k0 + jl * 8, true);
        } else {
          int gm = m0 + row, gk = k0 + jl * 8;
          xv = *(const bf16x8*)((const __bf16*)X +
                ((((size_t)(gm >> 11) * H_ + (gk >> 6)) * S_) +
                 (gm & (S_ - 1))) * DK_ + (gk & (DK_ - 1)));
        }
        *(bf16x8*)&As[row * 64 + j * 8] = xv;
      }
#pragma unroll
      for (int i = 0; i < TN / 32; ++i) {
        int c = t + 256 * i;
        int row = c >> 3, j = c & 7;
        int jl = j ^ (row & 7);
        bf16x8 wv = load8cvt(W, (size_t)(n0 + row) * Kd + k0 + jl * 8, true);
        *(bf16x8*)&Bs[row * 64 + j * 8] = wv;
      }
    }
    __syncthreads();

#pragma unroll
    for (int h = 0; h < 2; ++h) {
      bf16x8 af[MI], bfr[NI];
#pragma unroll
      for (int mi = 0; mi < MI; ++mi) {
        int row = wm + mi * 16 + l15;
        af[mi] = *(const bf16x8*)&As[row * 64 +
                                     (((h * 4 + quad) ^ (row & 7)) << 3)];
      }
#pragma unroll
      for (int ni = 0; ni < NI; ++ni) {
        int row = wn + ni * 16 + l15;
        bfr[ni] = *(const bf16x8*)&Bs[row * 64 +
                                      (((h * 4 + quad) ^ (row & 7)) << 3)];
      }
#pragma unroll
      for (int mi = 0; mi < MI; ++mi)
#pragma unroll
        for (int ni = 0; ni < NI; ++ni)
          acc[mi][ni] = __builtin_amdgcn_mfma_f32_16x16x32_bf16(
              af[mi], bfr[ni], acc[mi][ni], 0, 0, 0);
    }
  }

  const float oscale = (MODE == 0 && blockIdx.z == 0) ? QSCALE : 1.0f;
#pragma unroll
  for (int mi = 0; mi < MI; ++mi) {
#pragma unroll
    for (int ni = 0; ni < NI; ++ni) {
      int mbase = m0 + wm + mi * 16 + quad * 4;
      int n = n0 + wn + ni * 16 + l15;
      if (MODE == 0 && blockIdx.z == 2) {
        int b = mbase >> 11, sb = mbase & (S_ - 1);
        int h = n >> 6, dk = n & (DK_ - 1);
        bf16x4 pk;
#pragma unroll
        for (int r = 0; r < 4; ++r) pk[r] = (__bf16)acc[mi][ni][r];
        *(bf16x4*)&((__bf16*)O)[((size_t)(b * H_ + h) * DK_ + dk) * S_ + sb] = pk;
      } else {
#pragma unroll
        for (int r = 0; r < 4; ++r) {
          int m = mbase + r;
          float val = acc[mi][ni][r] * oscale;
          if (MODE == 0) {
            int b = m >> 11, s = m & (S_ - 1);
            int h = n >> 6, dk = n & (DK_ - 1);
            ((__bf16*)O)[((size_t)(b * H_ + h) * S_ + s) * DK_ + dk] = (__bf16)val;
          } else {
            size_t idx = (size_t)m * Nd + n;
            if (f32io) ((float*)O)[idx] = val;
            else       ((__bf16*)O)[idx] = (__bf16)val;
          }
        }
      }
    }
  }
}

// ---------------------------------------------------------------------------
// Flash attention, R11 form (verbatim, proven 75.6 us): 128 q-rows/block
// (32/wave as 2 q-tiles), 64 keys/iter, grid 512. Swapped score MFMA:
// s = mfma(Kfrag, Qfrag, bias) -> lane holds s[key=quad*4+r][q=l15].
// P per wave per q-tile: [16 q][64 key] rows of 128B, 16B chunks XOR-
// swizzled by (l15&7). Store: one ds_write_b64 per (qt,tt); read: one
// ds_read_b128 per (qt,kt) -> PV A-frag directly. K/V frags read once,
// shared by both q-tiles. Mask as per-key f32x4 bias init. Wave-private
// P: in-order LDS, no barriers; asm fence pins store phase above reads.
// ---------------------------------------------------------------------------
__global__ __launch_bounds__(256, 2) void attn(
    const __bf16* Qh, const __bf16* __restrict__ Kh,
    const __bf16* __restrict__ Vt, const int* __restrict__ mask,
    __bf16* Out) {
  __shared__ __attribute__((aligned(16))) __bf16 Ks[2][4096];
  __shared__ __attribute__((aligned(16))) __bf16 Vs[2][4096];
  __shared__ __attribute__((aligned(16))) __bf16 P[4][2048];  // wave: 2 x [16][64]

  const int t = threadIdx.x;
  const int lane = t & 63, wave = t >> 6;
  const int l15 = lane & 15, quad = lane >> 4;
  const int qb = blockIdx.x & 15;   // 16 q-blocks of 128
  const int bh = blockIdx.x >> 4;   // b*H + h
  const int b = bh >> 4;
  const int q0 = qb * 128 + wave * 32;

  const __bf16* Q = Qh + (size_t)bh * S_ * DK_;
  const __bf16* K = Kh + (size_t)bh * S_ * DK_;
  const __bf16* V = Vt + (size_t)bh * DK_ * S_;   // [dk][s]
  const int* mk = mask + b * S_;

  bf16x8 qf[2][2];
#pragma unroll
  for (int qt = 0; qt < 2; ++qt) {
    qf[qt][0] = *(const bf16x8*)&Q[(size_t)(q0 + qt * 16 + l15) * DK_ + quad * 8];
    qf[qt][1] = *(const bf16x8*)&Q[(size_t)(q0 + qt * 16 + l15) * DK_ + 32 + quad * 8];
  }

  f32x4 o[2][4] = {};
  float lsum[2] = {0.f, 0.f};

  // loop-invariant P element offsets (within P[wave], before qt*1024)
  int pst[4], prd[2];
#pragma unroll
  for (int tt = 0; tt < 4; ++tt)
    pst[tt] = l15 * 64 + (((tt * 2 + (quad >> 1)) ^ (l15 & 7)) << 3) +
              (quad & 1) * 4;
#pragma unroll
  for (int kt = 0; kt < 2; ++kt)
    prd[kt] = l15 * 64 + (((kt * 4 + quad) ^ (l15 & 7)) << 3);

  // prologue: stage tile 0 into buf 0
#pragma unroll
  for (int i = 0; i < 2; ++i) {
    int l = wave * 128 + i * 64 + lane;
    int row = l >> 3, jg = (l & 7) ^ (row & 7);
    async_cp16(K + (size_t)row * DK_ + jg * 8, &Ks[0][(size_t)(l - lane) * 8]);
    async_cp16(V + (size_t)row * S_ + jg * 8, &Vs[0][(size_t)(l - lane) * 8]);
  }
  __syncthreads();

  for (int kb = 0; kb < S_; kb += 64) {
    const int cur = (kb >> 6) & 1;
    if (kb + 64 < S_) {
#pragma unroll
      for (int i = 0; i < 2; ++i) {
        int l = wave * 128 + i * 64 + lane;
        int row = l >> 3, jg = (l & 7) ^ (row & 7);
        async_cp16(K + (size_t)(kb + 64 + row) * DK_ + jg * 8,
                   &Ks[cur ^ 1][(size_t)(l - lane) * 8]);
        async_cp16(V + (size_t)row * S_ + (kb + 64) + jg * 8,
                   &Vs[cur ^ 1][(size_t)(l - lane) * 8]);
      }
    }

    // ---- scores (SWAPPED): s[key=quad*4+r][q=l15]; K frags shared ----
    const __bf16* ks = &Ks[cur][0];
    f32x4 s[2][4];
#pragma unroll
    for (int tt = 0; tt < 4; ++tt) {
      int row = tt * 16 + l15;
      bf16x8 kf0 = *(const bf16x8*)&ks[row * 64 + ((quad ^ (l15 & 7)) << 3)];
      bf16x8 kf1 = *(const bf16x8*)&ks[row * 64 + (((4 + quad) ^ (l15 & 7)) << 3)];
      // per-key mask bias: keys tt*16 + quad*4 .. +3
      int4 m4 = *(const int4*)&mk[kb + tt * 16 + quad * 4];
      f32x4 z;
      z[0] = m4.x ? 0.f : -1e9f;
      z[1] = m4.y ? 0.f : -1e9f;
      z[2] = m4.z ? 0.f : -1e9f;
      z[3] = m4.w ? 0.f : -1e9f;
      f32x4 z0 = __builtin_amdgcn_mfma_f32_16x16x32_bf16(kf0, qf[0][0], z, 0, 0, 0);
      s[0][tt] = __builtin_amdgcn_mfma_f32_16x16x32_bf16(kf1, qf[0][1], z0, 0, 0, 0);
      f32x4 z1 = __builtin_amdgcn_mfma_f32_16x16x32_bf16(kf0, qf[1][0], z, 0, 0, 0);
      s[1][tt] = __builtin_amdgcn_mfma_f32_16x16x32_bf16(kf1, qf[1][1], z1, 0, 0, 0);
    }

    // ---- V fragments (issue while exp phase runs; shared by q-tiles) ----
    const __bf16* vs = &Vs[cur][0];
    bf16x8 vf[2][4];
#pragma unroll
    for (int kt = 0; kt < 2; ++kt)
#pragma unroll
      for (int nt = 0; nt < 4; ++nt) {
        int dk = nt * 16 + l15;
        vf[kt][nt] =
            *(const bf16x8*)&vs[dk * 64 + (((kt * 4 + quad) ^ (l15 & 7)) << 3)];
      }

    // ---- exp2 + packed P store: one b64 per (qt,tt) ----
#pragma unroll
    for (int qt = 0; qt < 2; ++qt) {
      float acc = 0.f;
#pragma unroll
      for (int tt = 0; tt < 4; ++tt) {
        bf16x4 pk;
#pragma unroll
        for (int r = 0; r < 4; ++r) {
          float e = __builtin_exp2f(s[qt][tt][r]);   // Q carries 0.125*log2e
          acc += e;
          pk[r] = (__bf16)e;
        }
        *(bf16x4*)&P[wave][qt * 1024 + pst[tt]] = pk;
      }
      lsum[qt] += acc;
    }

    asm volatile("" ::: "memory");  // pin P stores above the P reads (TBAA)

    // ---- PV: P read back as A-frag via b128; V frags shared ----
#pragma unroll
    for (int qt = 0; qt < 2; ++qt)
#pragma unroll
      for (int kt = 0; kt < 2; ++kt) {
        bf16x8 pf = *(const bf16x8*)&P[wave][qt * 1024 + prd[kt]];
#pragma unroll
        for (int nt = 0; nt < 4; ++nt)
          o[qt][nt] = __builtin_amdgcn_mfma_f32_16x16x32_bf16(
              pf, vf[kt][nt], o[qt][nt], 0, 0, 0);
      }

    __syncthreads();  // drains staging vmcnt; separates buffer reuse
  }

  // lsum finish: all keys of a q-row live in lanes with same l15
#pragma unroll
  for (int qt = 0; qt < 2; ++qt) {
    float v = lsum[qt];
    v += __shfl_xor(v, 16, 64);
    v += __shfl_xor(v, 32, 64);
    lsum[qt] = v;  // every lane: sum for q = l15 (of tile qt)
  }

#pragma unroll
  for (int qt = 0; qt < 2; ++qt) {
    float rinv[4];
#pragma unroll
    for (int r = 0; r < 4; ++r)
      rinv[r] = 1.0f / __shfl(lsum[qt], quad * 4 + r, 64);
#pragma unroll
    for (int nt = 0; nt < 4; ++nt)
#pragma unroll
      for (int r = 0; r < 4; ++r) {
        int qrow = q0 + qt * 16 + quad * 4 + r;
        Out[(size_t)bh * S_ * DK_ + (size_t)qrow * DK_ + nt * 16 + l15] =
            (__bf16)(o[qt][nt][r] * rinv[r]);
      }
  }
}

extern "C" void kernel_launch(void* const* d_in, const int* in_sizes, int n_in,
                              void* d_out, int out_size, void* d_ws, size_t ws_size,
                              hipStream_t stream) {
  const void* q = d_in[0];
  const void* k = d_in[1];
  const void* v = d_in[2];
  const int* mask = (const int*)d_in[3];
  const void* Wq = d_in[4];
  const void* Wk = d_in[5];
  const void* Wv = d_in[6];
  const void* Wo = d_in[7];

  const size_t NE = (size_t)B_ * H_ * S_ * DK_;  // 4,194,304 elems
  __bf16* Qh = (__bf16*)d_ws;                    // ws[0 : 8M)  -> becomes ctx
  __bf16* Kh = Qh + NE;                          // ws[8M : 16M)
  int* dflag = (int*)((char*)d_ws + 2 * NE * sizeof(__bf16));
  __bf16* Vt = (__bf16*)d_out;                   // scratch; dead before final write

  detect_dtype<<<1, 64, 0, stream>>>((const unsigned int*)q, dflag);
  dim3 g1(32, 8, 3);
  gemmk<128, 128, 0><<<g1, 256, 0, stream>>>(q, k, v, Wq, Wk, Wv, Qh, Kh, Vt,
                                             dflag);
  attn<<<512, 256, 0, stream>>>(Qh, Kh, Vt, mask, Qh);
  dim3 g2(64, 8, 1);
  gemmk<64, 128, 1><<<g2, 256, 0, stream>>>(Qh, Qh, Qh, Wo, Wo, Wo, d_out,
                                            d_out, d_out, dflag);
}

// Round 9
// 251.871 us; speedup vs baseline: 1.2267x; 1.0174x over previous
//
#include <hip/hip_runtime.h>

// MHA: B=2, S=2048, D=1024, H=16, DK=64. I/O bf16 (harness-confirmed R4);
// dual fp32 path retained via runtime inline detect. mask int32.
//
// Pipeline (ws 16 MB; d_out doubles as V scratch) -- 3 dispatches:
//   1) gemmk<128,128,0>: Q/K/V proj (one launch, z selects tensor).
//        z=0: Qh [B,H,S,DK] pre-scaled by 0.125*log2e; z=1: Kh;
//        z=2: Vt [B,H,DK,S] transposed.
//   2) attn (R11 + setprio + XCD swizzle): flash, 128 q-rows/block.
//   3) gemmk<64,128,1>: out = ctx @ Wo^T -> d_out (512 blocks).
//
// MFMA 16x16x32 bf16 layouts (verified):
//   A: lane holds A[m=lane&15][k=(lane>>4)*8+j]
//   B: lane holds B[k=(lane>>4)*8+j][n=lane&15]
//   C/D: col=lane&15, row=(lane>>4)*4+reg
//
// R4: no u16/bf16 punning (TBAA reorder -> NaN).
// R9/R16: BK=64 wins; BK=128 16-chunk XOR aliases banks (4.7M conflicts).
// R10 FAILED: ds_read_b64_tr_b16 gather model wrong.
// R11: swapped-MFMA packed-P attn 85.6 -> 75.6 us.
// R12-R17 gemm ladder: dbuf / 2x-occupancy / counted-vmcnt depth-3 /
//   BK=128 / 128x128-tile ALL flat-to-worse. Surviving model (fits all):
//   time = 16 serial K-steps x ~4.8us; step-time set by aggregate L2/L3
//   staging traffic (~295 MB logical/dispatch; W-panels re-read 32x and
//   SCATTERED across the 8 XCD-private L2s by round-robin dispatch).
//   The bound pipe has no counter in our set -> everything reads idle.
// R18 (this round): attack the L2/L3 traffic + overheads, zero schedule
//   changes: (1) T1 XCD-bijective swizzle on all three kernels (gemm:
//   each XCD gets a full m-run per n-panel -> W fetched once per XCD;
//   attn: whole bh-groups per XCD -> K/V L2-local). (2) T5 setprio on
//   attn MFMA clusters only (m191: +4-7% this regime; m190: not gemms).
//   (3) detect dispatch inlined into gemm waves (4 -> 3 dispatches).
//   Falsifier: FETCH flat AND dur flat => locality theory dead; residual
//   is fixed harness overhead.

typedef __bf16 bf16x8 __attribute__((ext_vector_type(8)));
typedef __bf16 bf16x4 __attribute__((ext_vector_type(4)));
typedef float f32x4 __attribute__((ext_vector_type(4)));

#define B_ 2
#define S_ 2048
#define D_ 1024
#define H_ 16
#define DK_ 64
#define QSCALE 0.18033688011112042f  // 0.125 * log2(e)

// ---------------------------------------------------------------------------
// per-wave inline dtype detect: classify first 256 words of q. bf16 pairs
// put a real exponent at bits [14:7]; f32 words put mantissa there.
// All waves read the same 1KB (L2-broadcast) and agree on the result.
__device__ __forceinline__ bool detect_f32_wave(const unsigned* qw, int lane) {
  int cnt = 0;
#pragma unroll
  for (int i = 0; i < 4; ++i) {
    unsigned w = qw[lane + 64 * i];
    int e = (w >> 7) & 0xFF;
    cnt += (e >= 100 && e <= 140) ? 1 : 0;
  }
#pragma unroll
  for (int off = 32; off > 0; off >>= 1) cnt += __shfl_down(cnt, off, 64);
  return __shfl(cnt, 0, 64) < 128;
}

__device__ __forceinline__ bf16x8 load8cvt(const void* base, size_t eoff,
                                           bool f32) {
  if (!f32) return *(const bf16x8*)((const __bf16*)base + eoff);
  const float* p = (const float*)base + eoff;
  bf16x8 r;
#pragma unroll
  for (int j = 0; j < 8; ++j) r[j] = (__bf16)p[j];
  return r;
}

// async 16B global -> LDS (lds dest = wave-uniform base + lane*16)
__device__ __forceinline__ void async_cp16(const __bf16* g, __bf16* l) {
  __builtin_amdgcn_global_load_lds(
      (const __attribute__((address_space(1))) unsigned int*)g,
      (__attribute__((address_space(3))) unsigned int*)l, 16, 0, 0);
}

// ---------------------------------------------------------------------------
// GEMM (R18): C[M,N] = X[M,K] @ W[N,K]^T, TM x TN tile, BK=64, single LDS
// buffer, proven 2-barrier K-step {barrier; stage; barrier; compute}.
// XCD swizzle: linear block id L -> chunk c=(L&7)*(NWG/8)+(L>>3); each
// XCD gets NWG/8 consecutive c = complete m-runs sharing the same W
// n-panel -> panel lives in that XCD's L2 (bijective: NWG%8==0).
// LDS [rows][64]; 16B chunks XOR-swizzled (phys j = jl ^ (row&7)) --
// the PROVEN zero-conflict BK=64 layout. Staging: linear LDS dest +
// pre-swizzled global source (rule #21). f32 fallback: reg-staged.
// ---------------------------------------------------------------------------
template <int TM, int TN, int MODE>
__global__ __launch_bounds__(256) void gemmk(
    const void* X0, const void* X1, const void* X2,
    const void* W0, const void* W1, const void* W2,
    void* O0, void* O1, void* O2, const unsigned* __restrict__ qdet) {
  constexpr int Kd = 1024, Nd = 1024;
  constexpr int MI = TM / 32;     // m-frags per wave
  constexpr int NI = TN / 32;     // n-frags per wave
  constexpr int ACH = TM / 32;    // A staging cp16 per wave (1KB each)
  constexpr int BCH = TN / 32;    // B staging cp16 per wave
  constexpr int GX = 4096 / TM;   // m-blocks
  constexpr int GY = 1024 / TN;   // n-blocks
  constexpr int NWG = GX * GY;    // per z-slice; 256 or 512 (both %8==0)
  const void* X = (blockIdx.z == 0) ? X0 : (blockIdx.z == 1 ? X1 : X2);
  const void* W = (blockIdx.z == 0) ? W0 : (blockIdx.z == 1 ? W1 : W2);
  void* O = (blockIdx.z == 0) ? O0 : (blockIdx.z == 1 ? O1 : O2);

  __shared__ __attribute__((aligned(16))) __bf16 As[TM * 64];
  __shared__ __attribute__((aligned(16))) __bf16 Bs[TN * 64];

  // XCD-bijective remap within the z-slice
  const int L = blockIdx.y * GX + blockIdx.x;
  const int c = (L & 7) * (NWG / 8) + (L >> 3);
  const int m0 = (c % GX) * TM;
  const int n0 = (c / GX) * TN;

  const int t = threadIdx.x;
  const int lane = t & 63, wave = t >> 6;
  const int l15 = lane & 15, quad = lane >> 4;
  const int wm = (wave >> 1) * (TM / 2);
  const int wn = (wave & 1) * (TN / 2);

  const bool f32io = detect_f32_wave(qdet, lane);

  const __bf16* gA[ACH];
  int ldsAoff[ACH];
#pragma unroll
  for (int i = 0; i < ACH; ++i) {
    int ci = (wave * ACH + i) * 64 + lane;
    int row = ci >> 3, j = ci & 7;
    int jl = j ^ (row & 7);
    ldsAoff[i] = (wave * ACH + i) * 512;
    if (MODE == 0) {
      gA[i] = (const __bf16*)X + (size_t)(m0 + row) * Kd + jl * 8;
    } else {
      int gm = m0 + row;
      gA[i] = (const __bf16*)X + (size_t)(gm >> 11) * (H_ * S_ * DK_) +
              (size_t)(gm & (S_ - 1)) * DK_ + jl * 8;
    }
  }
  const __bf16* gB[BCH];
  int ldsBoff[BCH];
#pragma unroll
  for (int i = 0; i < BCH; ++i) {
    int ci = (wave * BCH + i) * 64 + lane;
    int row = ci >> 3, j = ci & 7;
    int jl = j ^ (row & 7);
    ldsBoff[i] = (wave * BCH + i) * 512;
    gB[i] = (const __bf16*)W + (size_t)(n0 + row) * Kd + jl * 8;
  }

  f32x4 acc[MI][NI] = {};

  for (int k0 = 0; k0 < Kd; k0 += 64) {
    __syncthreads();
    if (!f32io) {
      if (MODE == 0) {
#pragma unroll
        for (int i = 0; i < ACH; ++i) async_cp16(gA[i] + k0, &As[ldsAoff[i]]);
      } else {
        const size_t koff = (size_t)(k0 >> 6) * (S_ * DK_);
#pragma unroll
        for (int i = 0; i < ACH; ++i) async_cp16(gA[i] + koff, &As[ldsAoff[i]]);
      }
#pragma unroll
      for (int i = 0; i < BCH; ++i) async_cp16(gB[i] + k0, &Bs[ldsBoff[i]]);
    } else {
#pragma unroll
      for (int i = 0; i < TM / 32; ++i) {
        int ci = t + 256 * i;
        int row = ci >> 3, j = ci & 7;
        int jl = j ^ (row & 7);
        bf16x8 xv;
        if (MODE == 0) {
          xv = load8cvt(X, (size_t)(m0 + row) * Kd + k0 + jl * 8, true);
        } else {
          int gm = m0 + row, gk = k0 + jl * 8;
          xv = *(const bf16x8*)((const __bf16*)X +
                ((((size_t)(gm >> 11) * H_ + (gk >> 6)) * S_) +
                 (gm & (S_ - 1))) * DK_ + (gk & (DK_ - 1)));
        }
        *(bf16x8*)&As[row * 64 + j * 8] = xv;
      }
#pragma unroll
      for (int i = 0; i < TN / 32; ++i) {
        int ci = t + 256 * i;
        int row = ci >> 3, j = ci & 7;
        int jl = j ^ (row & 7);
        bf16x8 wv = load8cvt(W, (size_t)(n0 + row) * Kd + k0 + jl * 8, true);
        *(bf16x8*)&Bs[row * 64 + j * 8] = wv;
      }
    }
    __syncthreads();

#pragma unroll
    for (int h = 0; h < 2; ++h) {
      bf16x8 af[MI], bfr[NI];
#pragma unroll
      for (int mi = 0; mi < MI; ++mi) {
        int row = wm + mi * 16 + l15;
        af[mi] = *(const bf16x8*)&As[row * 64 +
                                     (((h * 4 + quad) ^ (row & 7)) << 3)];
      }
#pragma unroll
      for (int ni = 0; ni < NI; ++ni) {
        int row = wn + ni * 16 + l15;
        bfr[ni] = *(const bf16x8*)&Bs[row * 64 +
                                      (((h * 4 + quad) ^ (row & 7)) << 3)];
      }
#pragma unroll
      for (int mi = 0; mi < MI; ++mi)
#pragma unroll
        for (int ni = 0; ni < NI; ++ni)
          acc[mi][ni] = __builtin_amdgcn_mfma_f32_16x16x32_bf16(
              af[mi], bfr[ni], acc[mi][ni], 0, 0, 0);
    }
  }

  const float oscale = (MODE == 0 && blockIdx.z == 0) ? QSCALE : 1.0f;
#pragma unroll
  for (int mi = 0; mi < MI; ++mi) {
#pragma unroll
    for (int ni = 0; ni < NI; ++ni) {
      int mbase = m0 + wm + mi * 16 + quad * 4;
      int n = n0 + wn + ni * 16 + l15;
      if (MODE == 0 && blockIdx.z == 2) {
        int b = mbase >> 11, sb = mbase & (S_ - 1);
        int h = n >> 6, dk = n & (DK_ - 1);
        bf16x4 pk;
#pragma unroll
        for (int r = 0; r < 4; ++r) pk[r] = (__bf16)acc[mi][ni][r];
        *(bf16x4*)&((__bf16*)O)[((size_t)(b * H_ + h) * DK_ + dk) * S_ + sb] = pk;
      } else {
#pragma unroll
        for (int r = 0; r < 4; ++r) {
          int m = mbase + r;
          float val = acc[mi][ni][r] * oscale;
          if (MODE == 0) {
            int b = m >> 11, s = m & (S_ - 1);
            int h = n >> 6, dk = n & (DK_ - 1);
            ((__bf16*)O)[((size_t)(b * H_ + h) * S_ + s) * DK_ + dk] = (__bf16)val;
          } else {
            size_t idx = (size_t)m * Nd + n;
            if (f32io) ((float*)O)[idx] = val;
            else       ((__bf16*)O)[idx] = (__bf16)val;
          }
        }
      }
    }
  }
}

// ---------------------------------------------------------------------------
// Flash attention (R18 = R11 + XCD swizzle + setprio): 128 q-rows/block
// (32/wave as 2 q-tiles), 64 keys/iter, grid 512. XCD swizzle gives each
// XCD 64 consecutive chunks = 4 complete bh-groups -> K/V L2-local.
// Swapped score MFMA: s = mfma(Kfrag, Qfrag, bias) -> lane holds
// s[key=quad*4+r][q=l15]. P per wave per q-tile: [16 q][64 key] rows of
// 128B, 16B chunks XOR-swizzled by (l15&7). Store: one ds_write_b64 per
// (qt,tt); read: one ds_read_b128 per (qt,kt) -> PV A-frag directly.
// K/V frags read once, shared by both q-tiles. T5 setprio around both
// MFMA clusters (m191 regime: independent blocks). Wave-private P:
// in-order LDS, no barriers; asm fence pins store phase above reads.
// ---------------------------------------------------------------------------
__global__ __launch_bounds__(256, 2) void attn(
    const __bf16* Qh, const __bf16* __restrict__ Kh,
    const __bf16* __restrict__ Vt, const int* __restrict__ mask,
    __bf16* Out) {
  __shared__ __attribute__((aligned(16))) __bf16 Ks[2][4096];
  __shared__ __attribute__((aligned(16))) __bf16 Vs[2][4096];
  __shared__ __attribute__((aligned(16))) __bf16 P[4][2048];  // wave: 2 x [16][64]

  const int t = threadIdx.x;
  const int lane = t & 63, wave = t >> 6;
  const int l15 = lane & 15, quad = lane >> 4;
  // XCD-bijective remap (512 = 8 x 64)
  const int L = blockIdx.x;
  const int c = (L & 7) * 64 + (L >> 3);
  const int qb = c & 15;            // 16 q-blocks of 128
  const int bh = c >> 4;            // b*H + h
  const int b = bh >> 4;
  const int q0 = qb * 128 + wave * 32;

  const __bf16* Q = Qh + (size_t)bh * S_ * DK_;
  const __bf16* K = Kh + (size_t)bh * S_ * DK_;
  const __bf16* V = Vt + (size_t)bh * DK_ * S_;   // [dk][s]
  const int* mk = mask + b * S_;

  bf16x8 qf[2][2];
#pragma unroll
  for (int qt = 0; qt < 2; ++qt) {
    qf[qt][0] = *(const bf16x8*)&Q[(size_t)(q0 + qt * 16 + l15) * DK_ + quad * 8];
    qf[qt][1] = *(const bf16x8*)&Q[(size_t)(q0 + qt * 16 + l15) * DK_ + 32 + quad * 8];
  }

  f32x4 o[2][4] = {};
  float lsum[2] = {0.f, 0.f};

  // loop-invariant P element offsets (within P[wave], before qt*1024)
  int pst[4], prd[2];
#pragma unroll
  for (int tt = 0; tt < 4; ++tt)
    pst[tt] = l15 * 64 + (((tt * 2 + (quad >> 1)) ^ (l15 & 7)) << 3) +
              (quad & 1) * 4;
#pragma unroll
  for (int kt = 0; kt < 2; ++kt)
    prd[kt] = l15 * 64 + (((kt * 4 + quad) ^ (l15 & 7)) << 3);

  // prologue: stage tile 0 into buf 0
#pragma unroll
  for (int i = 0; i < 2; ++i) {
    int l = wave * 128 + i * 64 + lane;
    int row = l >> 3, jg = (l & 7) ^ (row & 7);
    async_cp16(K + (size_t)row * DK_ + jg * 8, &Ks[0][(size_t)(l - lane) * 8]);
    async_cp16(V + (size_t)row * S_ + jg * 8, &Vs[0][(size_t)(l - lane) * 8]);
  }
  __syncthreads();

  for (int kb = 0; kb < S_; kb += 64) {
    const int cur = (kb >> 6) & 1;
    if (kb + 64 < S_) {
#pragma unroll
      for (int i = 0; i < 2; ++i) {
        int l = wave * 128 + i * 64 + lane;
        int row = l >> 3, jg = (l & 7) ^ (row & 7);
        async_cp16(K + (size_t)(kb + 64 + row) * DK_ + jg * 8,
                   &Ks[cur ^ 1][(size_t)(l - lane) * 8]);
        async_cp16(V + (size_t)row * S_ + (kb + 64) + jg * 8,
                   &Vs[cur ^ 1][(size_t)(l - lane) * 8]);
      }
    }

    // ---- scores (SWAPPED): s[key=quad*4+r][q=l15]; K frags shared ----
    const __bf16* ks = &Ks[cur][0];
    f32x4 s[2][4];
    __builtin_amdgcn_s_setprio(1);
#pragma unroll
    for (int tt = 0; tt < 4; ++tt) {
      int row = tt * 16 + l15;
      bf16x8 kf0 = *(const bf16x8*)&ks[row * 64 + ((quad ^ (l15 & 7)) << 3)];
      bf16x8 kf1 = *(const bf16x8*)&ks[row * 64 + (((4 + quad) ^ (l15 & 7)) << 3)];
      // per-key mask bias: keys tt*16 + quad*4 .. +3
      int4 m4 = *(const int4*)&mk[kb + tt * 16 + quad * 4];
      f32x4 z;
      z[0] = m4.x ? 0.f : -1e9f;
      z[1] = m4.y ? 0.f : -1e9f;
      z[2] = m4.z ? 0.f : -1e9f;
      z[3] = m4.w ? 0.f : -1e9f;
      f32x4 z0 = __builtin_amdgcn_mfma_f32_16x16x32_bf16(kf0, qf[0][0], z, 0, 0, 0);
      s[0][tt] = __builtin_amdgcn_mfma_f32_16x16x32_bf16(kf1, qf[0][1], z0, 0, 0, 0);
      f32x4 z1 = __builtin_amdgcn_mfma_f32_16x16x32_bf16(kf0, qf[1][0], z, 0, 0, 0);
      s[1][tt] = __builtin_amdgcn_mfma_f32_16x16x32_bf16(kf1, qf[1][1], z1, 0, 0, 0);
    }
    __builtin_amdgcn_s_setprio(0);

    // ---- V fragments (issue while exp phase runs; shared by q-tiles) ----
    const __bf16* vs = &Vs[cur][0];
    bf16x8 vf[2][4];
#pragma unroll
    for (int kt = 0; kt < 2; ++kt)
#pragma unroll
      for (int nt = 0; nt < 4; ++nt) {
        int dk = nt * 16 + l15;
        vf[kt][nt] =
            *(const bf16x8*)&vs[dk * 64 + (((kt * 4 + quad) ^ (l15 & 7)) << 3)];
      }

    // ---- exp2 + packed P store: one b64 per (qt,tt) ----
#pragma unroll
    for (int qt = 0; qt < 2; ++qt) {
      float acc = 0.f;
#pragma unroll
      for (int tt = 0; tt < 4; ++tt) {
        bf16x4 pk;
#pragma unroll
        for (int r = 0; r < 4; ++r) {
          float e = __builtin_exp2f(s[qt][tt][r]);   // Q carries 0.125*log2e
          acc += e;
          pk[r] = (__bf16)e;
        }
        *(bf16x4*)&P[wave][qt * 1024 + pst[tt]] = pk;
      }
      lsum[qt] += acc;
    }

    asm volatile("" ::: "memory");  // pin P stores above the P reads (TBAA)

    // ---- PV: P read back as A-frag via b128; V frags shared ----
    __builtin_amdgcn_s_setprio(1);
#pragma unroll
    for (int qt = 0; qt < 2; ++qt)
#pragma unroll
      for (int kt = 0; kt < 2; ++kt) {
        bf16x8 pf = *(const bf16x8*)&P[wave][qt * 1024 + prd[kt]];
#pragma unroll
        for (int nt = 0; nt < 4; ++nt)
          o[qt][nt] = __builtin_amdgcn_mfma_f32_16x16x32_bf16(
              pf, vf[kt][nt], o[qt][nt], 0, 0, 0);
      }
    __builtin_amdgcn_s_setprio(0);

    __syncthreads();  // drains staging vmcnt; separates buffer reuse
  }

  // lsum finish: all keys of a q-row live in lanes with same l15
#pragma unroll
  for (int qt = 0; qt < 2; ++qt) {
    float v = lsum[qt];
    v += __shfl_xor(v, 16, 64);
    v += __shfl_xor(v, 32, 64);
    lsum[qt] = v;  // every lane: sum for q = l15 (of tile qt)
  }

#pragma unroll
  for (int qt = 0; qt < 2; ++qt) {
    float rinv[4];
#pragma unroll
    for (int r = 0; r < 4; ++r)
      rinv[r] = 1.0f / __shfl(lsum[qt], quad * 4 + r, 64);
#pragma unroll
    for (int nt = 0; nt < 4; ++nt)
#pragma unroll
      for (int r = 0; r < 4; ++r) {
        int qrow = q0 + qt * 16 + quad * 4 + r;
        Out[(size_t)bh * S_ * DK_ + (size_t)qrow * DK_ + nt * 16 + l15] =
            (__bf16)(o[qt][nt][r] * rinv[r]);
      }
  }
}

extern "C" void kernel_launch(void* const* d_in, const int* in_sizes, int n_in,
                              void* d_out, int out_size, void* d_ws, size_t ws_size,
                              hipStream_t stream) {
  const void* q = d_in[0];
  const void* k = d_in[1];
  const void* v = d_in[2];
  const int* mask = (const int*)d_in[3];
  const void* Wq = d_in[4];
  const void* Wk = d_in[5];
  const void* Wv = d_in[6];
  const void* Wo = d_in[7];

  const size_t NE = (size_t)B_ * H_ * S_ * DK_;  // 4,194,304 elems
  __bf16* Qh = (__bf16*)d_ws;                    // ws[0 : 8M)  -> becomes ctx
  __bf16* Kh = Qh + NE;                          // ws[8M : 16M)
  __bf16* Vt = (__bf16*)d_out;                   // scratch; dead before final write

  dim3 g1(32, 8, 3);
  gemmk<128, 128, 0><<<g1, 256, 0, stream>>>(q, k, v, Wq, Wk, Wv, Qh, Kh, Vt,
                                             (const unsigned*)q);
  attn<<<512, 256, 0, stream>>>(Qh, Kh, Vt, mask, Qh);
  dim3 g2(64, 8, 1);
  gemmk<64, 128, 1><<<g2, 256, 0, stream>>>(Qh, Qh, Qh, Wo, Wo, Wo, d_out,
                                            d_out, d_out, (const unsigned*)q);
}

// Round 10
// 248.941 us; speedup vs baseline: 1.2411x; 1.0118x over previous
//
#include <hip/hip_runtime.h>

// MHA: B=2, S=2048, D=1024, H=16, DK=64. I/O bf16 (harness-confirmed R4);
// dual fp32 path retained via runtime inline detect. mask int32.
//
// Pipeline (ws 16 MB; d_out doubles as V scratch) -- 3 dispatches:
//   1) gemmk<128,128,0>: Q/K/V proj (one launch, z selects tensor).
//        z=0: Qh [B,H,S,DK] pre-scaled by 0.125*log2e; z=1: Kh;
//        z=2: Vt [B,H,DK,S] transposed.
//   2) attn (R18 form: R11 + setprio + XCD swizzle): 128 q-rows/block.
//   3) gemmk<64,128,1>: out = ctx @ Wo^T -> d_out (512 blocks).
//
// MFMA 16x16x32 bf16 layouts (verified):
//   A: lane holds A[m=lane&15][k=(lane>>4)*8+j]
//   B: lane holds B[k=(lane>>4)*8+j][n=lane&15]
//   C/D: col=lane&15, row=(lane>>4)*4+reg
//
// R4: no u16/bf16 punning (TBAA reorder -> NaN).
// R9/R16: BK=64 wins; BK=128 16-chunk XOR aliases banks.
// R10 FAILED: ds_read_b64_tr_b16 gather model wrong.
// R11: swapped-MFMA packed-P attn 85.6 -> 75.6 us.
// R12-R17 gemm ladder: dbuf / 2x-occupancy / counted-vmcnt / BK=128 /
//   128x128-tile ALL flat-to-worse; gemm time = 16 serial K-steps whose
//   step time is set by L2/L3 staging traffic.
// R18 (251.9, best): (a) attn XCD-swizzle + setprio = BIG WIN (~20-30us,
//   attn left the top-5); (b) gemm XCD-swizzle BACKFIRED: FETCH 73.8 ->
//   202.8 MB (each XCD streamed the FULL 8MB A through its 4MB L2; the
//   NATURAL round-robin already partitions A perfectly, m-panel ≡ x mod 8
//   -> one XCD's L2; W panels were never the problem). dur 76 -> 88-97.
// R19 (this round): revert gemm to natural block order (keep inline
//   detect); attn byte-identical to R18. Predict: QKV FETCH ~74MB,
//   dur ~76-79; attn now visible in top-5; total ~230us.

typedef __bf16 bf16x8 __attribute__((ext_vector_type(8)));
typedef __bf16 bf16x4 __attribute__((ext_vector_type(4)));
typedef float f32x4 __attribute__((ext_vector_type(4)));

#define B_ 2
#define S_ 2048
#define D_ 1024
#define H_ 16
#define DK_ 64
#define QSCALE 0.18033688011112042f  // 0.125 * log2(e)

// ---------------------------------------------------------------------------
// per-wave inline dtype detect: classify first 256 words of q. bf16 pairs
// put a real exponent at bits [14:7]; f32 words put mantissa there.
// All waves read the same 1KB (L2-broadcast) and agree on the result.
__device__ __forceinline__ bool detect_f32_wave(const unsigned* qw, int lane) {
  int cnt = 0;
#pragma unroll
  for (int i = 0; i < 4; ++i) {
    unsigned w = qw[lane + 64 * i];
    int e = (w >> 7) & 0xFF;
    cnt += (e >= 100 && e <= 140) ? 1 : 0;
  }
#pragma unroll
  for (int off = 32; off > 0; off >>= 1) cnt += __shfl_down(cnt, off, 64);
  return __shfl(cnt, 0, 64) < 128;
}

__device__ __forceinline__ bf16x8 load8cvt(const void* base, size_t eoff,
                                           bool f32) {
  if (!f32) return *(const bf16x8*)((const __bf16*)base + eoff);
  const float* p = (const float*)base + eoff;
  bf16x8 r;
#pragma unroll
  for (int j = 0; j < 8; ++j) r[j] = (__bf16)p[j];
  return r;
}

// async 16B global -> LDS (lds dest = wave-uniform base + lane*16)
__device__ __forceinline__ void async_cp16(const __bf16* g, __bf16* l) {
  __builtin_amdgcn_global_load_lds(
      (const __attribute__((address_space(1))) unsigned int*)g,
      (__attribute__((address_space(3))) unsigned int*)l, 16, 0, 0);
}

// ---------------------------------------------------------------------------
// GEMM (R19 = R17 + inline detect): C[M,N] = X[M,K] @ W[N,K]^T, TM x TN
// tile, BK=64, single LDS buffer, proven 2-barrier K-step {barrier; stage;
// barrier; compute}. NATURAL block order (measured-best: round-robin
// dispatch partitions A m-panels across XCD L2s; R18's swizzle tripled
// FETCH by streaming full A through each L2).
// LDS [rows][64]; 16B chunks XOR-swizzled (phys j = jl ^ (row&7)) --
// proven zero-conflict BK=64 layout. Staging: linear LDS dest +
// pre-swizzled global source (rule #21). f32 fallback: reg-staged.
// ---------------------------------------------------------------------------
template <int TM, int TN, int MODE>
__global__ __launch_bounds__(256) void gemmk(
    const void* X0, const void* X1, const void* X2,
    const void* W0, const void* W1, const void* W2,
    void* O0, void* O1, void* O2, const unsigned* __restrict__ qdet) {
  constexpr int Kd = 1024, Nd = 1024;
  constexpr int MI = TM / 32;     // m-frags per wave
  constexpr int NI = TN / 32;     // n-frags per wave
  constexpr int ACH = TM / 32;    // A staging cp16 per wave (1KB each)
  constexpr int BCH = TN / 32;    // B staging cp16 per wave
  const void* X = (blockIdx.z == 0) ? X0 : (blockIdx.z == 1 ? X1 : X2);
  const void* W = (blockIdx.z == 0) ? W0 : (blockIdx.z == 1 ? W1 : W2);
  void* O = (blockIdx.z == 0) ? O0 : (blockIdx.z == 1 ? O1 : O2);

  __shared__ __attribute__((aligned(16))) __bf16 As[TM * 64];
  __shared__ __attribute__((aligned(16))) __bf16 Bs[TN * 64];

  const int m0 = blockIdx.x * TM;
  const int n0 = blockIdx.y * TN;
  const int t = threadIdx.x;
  const int lane = t & 63, wave = t >> 6;
  const int l15 = lane & 15, quad = lane >> 4;
  const int wm = (wave >> 1) * (TM / 2);
  const int wn = (wave & 1) * (TN / 2);

  const bool f32io = detect_f32_wave(qdet, lane);

  const __bf16* gA[ACH];
  int ldsAoff[ACH];
#pragma unroll
  for (int i = 0; i < ACH; ++i) {
    int ci = (wave * ACH + i) * 64 + lane;
    int row = ci >> 3, j = ci & 7;
    int jl = j ^ (row & 7);
    ldsAoff[i] = (wave * ACH + i) * 512;
    if (MODE == 0) {
      gA[i] = (const __bf16*)X + (size_t)(m0 + row) * Kd + jl * 8;
    } else {
      int gm = m0 + row;
      gA[i] = (const __bf16*)X + (size_t)(gm >> 11) * (H_ * S_ * DK_) +
              (size_t)(gm & (S_ - 1)) * DK_ + jl * 8;
    }
  }
  const __bf16* gB[BCH];
  int ldsBoff[BCH];
#pragma unroll
  for (int i = 0; i < BCH; ++i) {
    int ci = (wave * BCH + i) * 64 + lane;
    int row = ci >> 3, j = ci & 7;
    int jl = j ^ (row & 7);
    ldsBoff[i] = (wave * BCH + i) * 512;
    gB[i] = (const __bf16*)W + (size_t)(n0 + row) * Kd + jl * 8;
  }

  f32x4 acc[MI][NI] = {};

  for (int k0 = 0; k0 < Kd; k0 += 64) {
    __syncthreads();
    if (!f32io) {
      if (MODE == 0) {
#pragma unroll
        for (int i = 0; i < ACH; ++i) async_cp16(gA[i] + k0, &As[ldsAoff[i]]);
      } else {
        const size_t koff = (size_t)(k0 >> 6) * (S_ * DK_);
#pragma unroll
        for (int i = 0; i < ACH; ++i) async_cp16(gA[i] + koff, &As[ldsAoff[i]]);
      }
#pragma unroll
      for (int i = 0; i < BCH; ++i) async_cp16(gB[i] + k0, &Bs[ldsBoff[i]]);
    } else {
#pragma unroll
      for (int i = 0; i < TM / 32; ++i) {
        int ci = t + 256 * i;
        int row = ci >> 3, j = ci & 7;
        int jl = j ^ (row & 7);
        bf16x8 xv;
        if (MODE == 0) {
          xv = load8cvt(X, (size_t)(m0 + row) * Kd + k0 + jl * 8, true);
        } else {
          int gm = m0 + row, gk = k0 + jl * 8;
          xv = *(const bf16x8*)((const __bf16*)X +
                ((((size_t)(gm >> 11) * H_ + (gk >> 6)) * S_) +
                 (gm & (S_ - 1))) * DK_ + (gk & (DK_ - 1)));
        }
        *(bf16x8*)&As[row * 64 + j * 8] = xv;
      }
#pragma unroll
      for (int i = 0; i < TN / 32; ++i) {
        int ci = t + 256 * i;
        int row = ci >> 3, j = ci & 7;
        int jl = j ^ (row & 7);
        bf16x8 wv = load8cvt(W, (size_t)(n0 + row) * Kd + k0 + jl * 8, true);
        *(bf16x8*)&Bs[row * 64 + j * 8] = wv;
      }
    }
    __syncthreads();

#pragma unroll
    for (int h = 0; h < 2; ++h) {
      bf16x8 af[MI], bfr[NI];
#pragma unroll
      for (int mi = 0; mi < MI; ++mi) {
        int row = wm + mi * 16 + l15;
        af[mi] = *(const bf16x8*)&As[row * 64 +
                                     (((h * 4 + quad) ^ (row & 7)) << 3)];
      }
#pragma unroll
      for (int ni = 0; ni < NI; ++ni) {
        int row = wn + ni * 16 + l15;
        bfr[ni] = *(const bf16x8*)&Bs[row * 64 +
                                      (((h * 4 + quad) ^ (row & 7)) << 3)];
      }
#pragma unroll
      for (int mi = 0; mi < MI; ++mi)
#pragma unroll
        for (int ni = 0; ni < NI; ++ni)
          acc[mi][ni] = __builtin_amdgcn_mfma_f32_16x16x32_bf16(
              af[mi], bfr[ni], acc[mi][ni], 0, 0, 0);
    }
  }

  const float oscale = (MODE == 0 && blockIdx.z == 0) ? QSCALE : 1.0f;
#pragma unroll
  for (int mi = 0; mi < MI; ++mi) {
#pragma unroll
    for (int ni = 0; ni < NI; ++ni) {
      int mbase = m0 + wm + mi * 16 + quad * 4;
      int n = n0 + wn + ni * 16 + l15;
      if (MODE == 0 && blockIdx.z == 2) {
        int b = mbase >> 11, sb = mbase & (S_ - 1);
        int h = n >> 6, dk = n & (DK_ - 1);
        bf16x4 pk;
#pragma unroll
        for (int r = 0; r < 4; ++r) pk[r] = (__bf16)acc[mi][ni][r];
        *(bf16x4*)&((__bf16*)O)[((size_t)(b * H_ + h) * DK_ + dk) * S_ + sb] = pk;
      } else {
#pragma unroll
        for (int r = 0; r < 4; ++r) {
          int m = mbase + r;
          float val = acc[mi][ni][r] * oscale;
          if (MODE == 0) {
            int b = m >> 11, s = m & (S_ - 1);
            int h = n >> 6, dk = n & (DK_ - 1);
            ((__bf16*)O)[((size_t)(b * H_ + h) * S_ + s) * DK_ + dk] = (__bf16)val;
          } else {
            size_t idx = (size_t)m * Nd + n;
            if (f32io) ((float*)O)[idx] = val;
            else       ((__bf16*)O)[idx] = (__bf16)val;
          }
        }
      }
    }
  }
}

// ---------------------------------------------------------------------------
// Flash attention (R18 form, byte-identical): 128 q-rows/block (32/wave
// as 2 q-tiles), 64 keys/iter, grid 512. XCD-bijective swizzle gives each
// XCD 64 consecutive chunks = 4 complete bh-groups -> K/V L2-local.
// Swapped score MFMA: s = mfma(Kfrag, Qfrag, bias) -> lane holds
// s[key=quad*4+r][q=l15]. P per wave per q-tile: [16 q][64 key] rows of
// 128B, 16B chunks XOR-swizzled by (l15&7). Store: one ds_write_b64 per
// (qt,tt); read: one ds_read_b128 per (qt,kt) -> PV A-frag directly.
// K/V frags read once, shared by both q-tiles. T5 setprio around both
// MFMA clusters. Wave-private P: in-order LDS, no barriers; asm fence
// pins store phase above reads.
// ---------------------------------------------------------------------------
__global__ __launch_bounds__(256, 2) void attn(
    const __bf16* Qh, const __bf16* __restrict__ Kh,
    const __bf16* __restrict__ Vt, const int* __restrict__ mask,
    __bf16* Out) {
  __shared__ __attribute__((aligned(16))) __bf16 Ks[2][4096];
  __shared__ __attribute__((aligned(16))) __bf16 Vs[2][4096];
  __shared__ __attribute__((aligned(16))) __bf16 P[4][2048];  // wave: 2 x [16][64]

  const int t = threadIdx.x;
  const int lane = t & 63, wave = t >> 6;
  const int l15 = lane & 15, quad = lane >> 4;
  // XCD-bijective remap (512 = 8 x 64)
  const int L = blockIdx.x;
  const int c = (L & 7) * 64 + (L >> 3);
  const int qb = c & 15;            // 16 q-blocks of 128
  const int bh = c >> 4;            // b*H + h
  const int b = bh >> 4;
  const int q0 = qb * 128 + wave * 32;

  const __bf16* Q = Qh + (size_t)bh * S_ * DK_;
  const __bf16* K = Kh + (size_t)bh * S_ * DK_;
  const __bf16* V = Vt + (size_t)bh * DK_ * S_;   // [dk][s]
  const int* mk = mask + b * S_;

  bf16x8 qf[2][2];
#pragma unroll
  for (int qt = 0; qt < 2; ++qt) {
    qf[qt][0] = *(const bf16x8*)&Q[(size_t)(q0 + qt * 16 + l15) * DK_ + quad * 8];
    qf[qt][1] = *(const bf16x8*)&Q[(size_t)(q0 + qt * 16 + l15) * DK_ + 32 + quad * 8];
  }

  f32x4 o[2][4] = {};
  float lsum[2] = {0.f, 0.f};

  // loop-invariant P element offsets (within P[wave], before qt*1024)
  int pst[4], prd[2];
#pragma unroll
  for (int tt = 0; tt < 4; ++tt)
    pst[tt] = l15 * 64 + (((tt * 2 + (quad >> 1)) ^ (l15 & 7)) << 3) +
              (quad & 1) * 4;
#pragma unroll
  for (int kt = 0; kt < 2; ++kt)
    prd[kt] = l15 * 64 + (((kt * 4 + quad) ^ (l15 & 7)) << 3);

  // prologue: stage tile 0 into buf 0
#pragma unroll
  for (int i = 0; i < 2; ++i) {
    int l = wave * 128 + i * 64 + lane;
    int row = l >> 3, jg = (l & 7) ^ (row & 7);
    async_cp16(K + (size_t)row * DK_ + jg * 8, &Ks[0][(size_t)(l - lane) * 8]);
    async_cp16(V + (size_t)row * S_ + jg * 8, &Vs[0][(size_t)(l - lane) * 8]);
  }
  __syncthreads();

  for (int kb = 0; kb < S_; kb += 64) {
    const int cur = (kb >> 6) & 1;
    if (kb + 64 < S_) {
#pragma unroll
      for (int i = 0; i < 2; ++i) {
        int l = wave * 128 + i * 64 + lane;
        int row = l >> 3, jg = (l & 7) ^ (row & 7);
        async_cp16(K + (size_t)(kb + 64 + row) * DK_ + jg * 8,
                   &Ks[cur ^ 1][(size_t)(l - lane) * 8]);
        async_cp16(V + (size_t)row * S_ + (kb + 64) + jg * 8,
                   &Vs[cur ^ 1][(size_t)(l - lane) * 8]);
      }
    }

    // ---- scores (SWAPPED): s[key=quad*4+r][q=l15]; K frags shared ----
    const __bf16* ks = &Ks[cur][0];
    f32x4 s[2][4];
    __builtin_amdgcn_s_setprio(1);
#pragma unroll
    for (int tt = 0; tt < 4; ++tt) {
      int row = tt * 16 + l15;
      bf16x8 kf0 = *(const bf16x8*)&ks[row * 64 + ((quad ^ (l15 & 7)) << 3)];
      bf16x8 kf1 = *(const bf16x8*)&ks[row * 64 + (((4 + quad) ^ (l15 & 7)) << 3)];
      // per-key mask bias: keys tt*16 + quad*4 .. +3
      int4 m4 = *(const int4*)&mk[kb + tt * 16 + quad * 4];
      f32x4 z;
      z[0] = m4.x ? 0.f : -1e9f;
      z[1] = m4.y ? 0.f : -1e9f;
      z[2] = m4.z ? 0.f : -1e9f;
      z[3] = m4.w ? 0.f : -1e9f;
      f32x4 z0 = __builtin_amdgcn_mfma_f32_16x16x32_bf16(kf0, qf[0][0], z, 0, 0, 0);
      s[0][tt] = __builtin_amdgcn_mfma_f32_16x16x32_bf16(kf1, qf[0][1], z0, 0, 0, 0);
      f32x4 z1 = __builtin_amdgcn_mfma_f32_16x16x32_bf16(kf0, qf[1][0], z, 0, 0, 0);
      s[1][tt] = __builtin_amdgcn_mfma_f32_16x16x32_bf16(kf1, qf[1][1], z1, 0, 0, 0);
    }
    __builtin_amdgcn_s_setprio(0);

    // ---- V fragments (issue while exp phase runs; shared by q-tiles) ----
    const __bf16* vs = &Vs[cur][0];
    bf16x8 vf[2][4];
#pragma unroll
    for (int kt = 0; kt < 2; ++kt)
#pragma unroll
      for (int nt = 0; nt < 4; ++nt) {
        int dk = nt * 16 + l15;
        vf[kt][nt] =
            *(const bf16x8*)&vs[dk * 64 + (((kt * 4 + quad) ^ (l15 & 7)) << 3)];
      }

    // ---- exp2 + packed P store: one b64 per (qt,tt) ----
#pragma unroll
    for (int qt = 0; qt < 2; ++qt) {
      float acc = 0.f;
#pragma unroll
      for (int tt = 0; tt < 4; ++tt) {
        bf16x4 pk;
#pragma unroll
        for (int r = 0; r < 4; ++r) {
          float e = __builtin_exp2f(s[qt][tt][r]);   // Q carries 0.125*log2e
          acc += e;
          pk[r] = (__bf16)e;
        }
        *(bf16x4*)&P[wave][qt * 1024 + pst[tt]] = pk;
      }
      lsum[qt] += acc;
    }

    asm volatile("" ::: "memory");  // pin P stores above the P reads (TBAA)

    // ---- PV: P read back as A-frag via b128; V frags shared ----
    __builtin_amdgcn_s_setprio(1);
#pragma unroll
    for (int qt = 0; qt < 2; ++qt)
#pragma unroll
      for (int kt = 0; kt < 2; ++kt) {
        bf16x8 pf = *(const bf16x8*)&P[wave][qt * 1024 + prd[kt]];
#pragma unroll
        for (int nt = 0; nt < 4; ++nt)
          o[qt][nt] = __builtin_amdgcn_mfma_f32_16x16x32_bf16(
              pf, vf[kt][nt], o[qt][nt], 0, 0, 0);
      }
    __builtin_amdgcn_s_setprio(0);

    __syncthreads();  // drains staging vmcnt; separates buffer reuse
  }

  // lsum finish: all keys of a q-row live in lanes with same l15
#pragma unroll
  for (int qt = 0; qt < 2; ++qt) {
    float v = lsum[qt];
    v += __shfl_xor(v, 16, 64);
    v += __shfl_xor(v, 32, 64);
    lsum[qt] = v;  // every lane: sum for q = l15 (of tile qt)
  }

#pragma unroll
  for (int qt = 0; qt < 2; ++qt) {
    float rinv[4];
#pragma unroll
    for (int r = 0; r < 4; ++r)
      rinv[r] = 1.0f / __shfl(lsum[qt], quad * 4 + r, 64);
#pragma unroll
    for (int nt = 0; nt < 4; ++nt)
#pragma unroll
      for (int r = 0; r < 4; ++r) {
        int qrow = q0 + qt * 16 + quad * 4 + r;
        Out[(size_t)bh * S_ * DK_ + (size_t)qrow * DK_ + nt * 16 + l15] =
            (__bf16)(o[qt][nt][r] * rinv[r]);
      }
  }
}

extern "C" void kernel_launch(void* const* d_in, const int* in_sizes, int n_in,
                              void* d_out, int out_size, void* d_ws, size_t ws_size,
                              hipStream_t stream) {
  const void* q = d_in[0];
  const void* k = d_in[1];
  const void* v = d_in[2];
  const int* mask = (const int*)d_in[3];
  const void* Wq = d_in[4];
  const void* Wk = d_in[5];
  const void* Wv = d_in[6];
  const void* Wo = d_in[7];

  const size_t NE = (size_t)B_ * H_ * S_ * DK_;  // 4,194,304 elems
  __bf16* Qh = (__bf16*)d_ws;                    // ws[0 : 8M)  -> becomes ctx
  __bf16* Kh = Qh + NE;                          // ws[8M : 16M)
  __bf16* Vt = (__bf16*)d_out;                   // scratch; dead before final write

  dim3 g1(32, 8, 3);
  gemmk<128, 128, 0><<<g1, 256, 0, stream>>>(q, k, v, Wq, Wk, Wv, Qh, Kh, Vt,
                                             (const unsigned*)q);
  attn<<<512, 256, 0, stream>>>(Qh, Kh, Vt, mask, Qh);
  dim3 g2(64, 8, 1);
  gemmk<64, 128, 1><<<g2, 256, 0, stream>>>(Qh, Qh, Qh, Wo, Wo, Wo, d_out,
                                            d_out, d_out, (const unsigned*)q);
}